// Round 11
// baseline (23765.044 us; speedup 1.0000x reference)
//
#include <hip/hip_runtime.h>
#include <math.h>

#define KP 8192
#define TSTEPS 4096
#define TSTEPS_CORE 2048     // experiment runs half the steps (cost scales linearly)
#define BLOCK 1024
#define PT 8
#define NWAVES 16
#define NBUCK 8192
#define NBF 8192.0f

// ---------------- DPP wave-scan helpers (pure VALU, no LDS pipe) ----------------
template <int CTRL, int RM>
__device__ __forceinline__ float dpp_add_f(float x) {
  int s = __builtin_amdgcn_update_dpp(0, __float_as_int(x), CTRL, RM, 0xF, false);
  return x + __int_as_float(s);
}
template <int CTRL, int RM>
__device__ __forceinline__ int dpp_max_i(int x) {
  int s = __builtin_amdgcn_update_dpp(0, x, CTRL, RM, 0xF, false);
  return x > s ? x : s;
}
__device__ __forceinline__ float wscan64_add(float x) {
  x = dpp_add_f<0x111, 0xF>(x); x = dpp_add_f<0x112, 0xF>(x);
  x = dpp_add_f<0x114, 0xF>(x); x = dpp_add_f<0x118, 0xF>(x);
  x = dpp_add_f<0x142, 0xA>(x); x = dpp_add_f<0x143, 0xC>(x);
  return x;
}
__device__ __forceinline__ int wscan64_max(int x) {
  x = dpp_max_i<0x111, 0xF>(x); x = dpp_max_i<0x112, 0xF>(x);
  x = dpp_max_i<0x114, 0xF>(x); x = dpp_max_i<0x118, 0xF>(x);
  x = dpp_max_i<0x142, 0xA>(x); x = dpp_max_i<0x143, 0xC>(x);
  return x;
}
__device__ __forceinline__ float rscan16_add(float x) {
  x = dpp_add_f<0x111, 0xF>(x); x = dpp_add_f<0x112, 0xF>(x);
  x = dpp_add_f<0x114, 0xF>(x); x = dpp_add_f<0x118, 0xF>(x);
  return x;
}
__device__ __forceinline__ int rscan16_max(int x) {
  x = dpp_max_i<0x111, 0xF>(x); x = dpp_max_i<0x112, 0xF>(x);
  x = dpp_max_i<0x114, 0xF>(x); x = dpp_max_i<0x118, 0xF>(x);
  return x;
}
__device__ __forceinline__ float readlane_f(float v, int l) {
  return __int_as_float(__builtin_amdgcn_readlane(__float_as_int(v), l));
}

// ---------------------------------------------------------------------------
// Transpose z [KP][TSTEPS] -> zT [TSTEPS][KP].
// ---------------------------------------------------------------------------
__global__ void transpose_k(const float* __restrict__ in, float* __restrict__ out) {
  __shared__ float tile[32][33];
  const int c0 = blockIdx.x * 32;
  const int r0 = blockIdx.y * 32;
  const int tx = threadIdx.x;
  const int ty = threadIdx.y;
#pragma unroll
  for (int i = 0; i < 32; i += 8)
    tile[ty + i][tx] = in[(size_t)(r0 + ty + i) * TSTEPS + c0 + tx];
  __syncthreads();
#pragma unroll
  for (int i = 0; i < 32; i += 8)
    out[(size_t)(c0 + ty + i) * KP + r0 + tx] = tile[tx][ty + i];
}

// ---------------------------------------------------------------------------
// EXPERIMENT: core-floor kernel. Identical A/B/cdf phases to production, but
// resampling machinery (bucket table, scatter, max-scan, binary search) is
// REPLACED by a fixed-permutation LDS gather (preserves: sequential t-chain,
// cdf write, cross-thread gather, double-buffer write-back, prefetch loads).
// 2 barriers/step. Writes its checksum to scratch; NOT used for d_out.
// Measures the irreducible core cost C_min by dur-subtraction.
// ---------------------------------------------------------------------------
__global__ __launch_bounds__(BLOCK) void smc_core(const float* __restrict__ x,
                                                  const float* __restrict__ w0,
                                                  const float* __restrict__ zsrc,
                                                  const float* __restrict__ u,
                                                  float* __restrict__ out_scratch) {
  extern __shared__ float sm[];
  float* wbufA = sm;
  float* wbufB = sm + KP;
  float* cdf_s = sm + 2 * KP;
  float* red = cdf_s + KP;

  const int tid = threadIdx.x;
  const int lane = tid & 63;
  const int wid = tid >> 6;
  const int kbase = tid * PT;

  float* wcur = wbufA;
  float* wnxt = wbufB;

  float wv[PT];
  {
    float4 a = *(const float4*)(w0 + kbase);
    float4 b = *(const float4*)(w0 + kbase + 4);
    wv[0] = a.x; wv[1] = a.y; wv[2] = a.z; wv[3] = a.w;
    wv[4] = b.x; wv[5] = b.y; wv[6] = b.z; wv[7] = b.w;
    *(float4*)(wcur + kbase) = a;
    *(float4*)(wcur + kbase + 4) = b;
  }
  __syncthreads();

  float zn[PT], un[PT];
  float xt_next = x[0];
  {
    float4 a = *(const float4*)(zsrc + kbase);
    float4 b = *(const float4*)(zsrc + kbase + 4);
    zn[0] = a.x; zn[1] = a.y; zn[2] = a.z; zn[3] = a.w;
    zn[4] = b.x; zn[5] = b.y; zn[6] = b.z; zn[7] = b.w;
  }
  {
    float4 a = *(const float4*)(u + kbase);
    float4 b = *(const float4*)(u + kbase + 4);
    un[0] = a.x; un[1] = a.y; un[2] = a.z; un[3] = a.w;
    un[4] = b.x; un[5] = b.y; un[6] = b.z; un[7] = b.w;
  }

  float acc = 0.f;

  for (int t = 0; t < TSTEPS_CORE; ++t) {
    float zv[PT], uv[PT];
#pragma unroll
    for (int j = 0; j < PT; ++j) { zv[j] = zn[j]; uv[j] = un[j]; }
    const float xt = xt_next;

    if (t + 1 < TSTEPS_CORE) {
      xt_next = x[t + 1];
      float4 a = *(const float4*)(zsrc + (size_t)(t + 1) * KP + kbase);
      float4 b = *(const float4*)(zsrc + (size_t)(t + 1) * KP + kbase + 4);
      zn[0] = a.x; zn[1] = a.y; zn[2] = a.z; zn[3] = a.w;
      zn[4] = b.x; zn[5] = b.y; zn[6] = b.z; zn[7] = b.w;
      float4 c = *(const float4*)(u + (size_t)(t + 1) * KP + kbase);
      float4 d = *(const float4*)(u + (size_t)(t + 1) * KP + kbase + 4);
      un[0] = c.x; un[1] = c.y; un[2] = c.z; un[3] = c.w;
      un[4] = d.x; un[5] = d.y; un[6] = d.z; un[7] = d.w;
    }
    // Keep u loads live without using them (rule 17: prevent DCE of the
    // stream an oracle resampler would still need).
#pragma unroll
    for (int j = 0; j < PT; ++j) asm volatile("" ::"v"(uv[j]));

    // ---- A: identical to production.
    float s[PT];
    float run = 0.f;
#pragma unroll
    for (int j = 0; j < PT; ++j) {
      float d = zv[j] - wv[j];
      float lw = fmaf(xt, zv[j], -0.5f * d * d);
      run += __expf(lw);
      s[j] = run;
    }
    const float wincl = wscan64_add(run);
    const float wexcl = wincl - run;
    if (lane == 63) red[wid] = wincl;
    __syncthreads();  // B1

    // ---- B: identical.
    float v16 = rscan16_add(red[lane & 15]);
    const float total = readlane_f(v16, 15);
    const float wpre = wid ? readlane_f(v16, wid - 1) : 0.f;
    const float base = wpre + wexcl;
    const float invT = 1.0f / total;

    // ---- C1: cdf write (identical cost).
    {
      float4 a, b;
      a.x = (base + s[0]) * invT; a.y = (base + s[1]) * invT;
      a.z = (base + s[2]) * invT; a.w = (base + s[3]) * invT;
      b.x = (base + s[4]) * invT; b.y = (base + s[5]) * invT;
      b.z = (base + s[6]) * invT; b.w = (base + s[7]) * invT;
      *(float4*)(cdf_s + kbase) = a;
      *(float4*)(cdf_s + kbase + 4) = b;
    }
    if (tid == 0)
      acc += __logf(total) - 9.0109133472792886f
             - 0.5f * (1.8378770664093453f + xt * xt);
    __syncthreads();  // B2

    // ---- ORACLE resample: fixed-permutation cross-thread gather (stands in
    // for search+scatter+scan; preserves gather + write-back + dependence).
    float nw[PT];
#pragma unroll
    for (int j = 0; j < PT; ++j) {
      float v = cdf_s[(kbase + j * 1031 + 4096) & (KP - 1)];
      nw[j] = fmaf(2.0f, v, -1.0f);  // bounded fake particle values
    }
    {
      float4 a, b;
      a.x = nw[0]; a.y = nw[1]; a.z = nw[2]; a.w = nw[3];
      b.x = nw[4]; b.y = nw[5]; b.z = nw[6]; b.w = nw[7];
      *(float4*)(wnxt + kbase) = a;
      *(float4*)(wnxt + kbase + 4) = b;
    }
#pragma unroll
    for (int j = 0; j < PT; ++j) wv[j] = nw[j];
    float* tmp = wcur; wcur = wnxt; wnxt = tmp;
  }

  if (tid == 0) out_scratch[0] = acc;
}

// ---------------------------------------------------------------------------
// PRODUCTION: proven round-6 kernel (absmax 0.0, ~20.9 ms).
// ---------------------------------------------------------------------------
template <bool ZTRANS>
__global__ __launch_bounds__(BLOCK) void smc_scan(const float* __restrict__ x,
                                                  const float* __restrict__ w0,
                                                  const float* __restrict__ zsrc,
                                                  const float* __restrict__ u,
                                                  float* __restrict__ out) {
  extern __shared__ float sm[];
  float* wbufA = sm;
  float* wbufB = sm + KP;
  float* cdf_s = sm + 2 * KP;
  float* cend = cdf_s + KP;
  float* red = cend + BLOCK;
  int* redi = (int*)(red + NWAVES);
  int* bcI = redi + NWAVES;
  int* L_s = bcI + 4;

  const int tid = threadIdx.x;
  const int lane = tid & 63;
  const int wid = tid >> 6;
  const int kbase = tid * PT;

  float* wcur = wbufA;
  float* wnxt = wbufB;

  for (int i = tid; i < NBUCK; i += BLOCK) L_s[i] = 0;
  if (tid == 0) L_s[NBUCK] = KP - 1;

  float wv[PT];
  {
    float4 a = *(const float4*)(w0 + kbase);
    float4 b = *(const float4*)(w0 + kbase + 4);
    wv[0] = a.x; wv[1] = a.y; wv[2] = a.z; wv[3] = a.w;
    wv[4] = b.x; wv[5] = b.y; wv[6] = b.z; wv[7] = b.w;
    *(float4*)(wcur + kbase) = a;
    *(float4*)(wcur + kbase + 4) = b;
  }
  __syncthreads();

  float zn[PT], un[PT];
  float xt_next = x[0];
  if (ZTRANS) {
    float4 a = *(const float4*)(zsrc + kbase);
    float4 b = *(const float4*)(zsrc + kbase + 4);
    zn[0] = a.x; zn[1] = a.y; zn[2] = a.z; zn[3] = a.w;
    zn[4] = b.x; zn[5] = b.y; zn[6] = b.z; zn[7] = b.w;
  } else {
#pragma unroll
    for (int j = 0; j < PT; ++j) zn[j] = zsrc[(size_t)(kbase + j) * TSTEPS];
  }
  {
    float4 a = *(const float4*)(u + kbase);
    float4 b = *(const float4*)(u + kbase + 4);
    un[0] = a.x; un[1] = a.y; un[2] = a.z; un[3] = a.w;
    un[4] = b.x; un[5] = b.y; un[6] = b.z; un[7] = b.w;
  }

  float acc = 0.f;

  for (int t = 0; t < TSTEPS; ++t) {
    float zv[PT], uv[PT];
#pragma unroll
    for (int j = 0; j < PT; ++j) { zv[j] = zn[j]; uv[j] = un[j]; }
    const float xt = xt_next;

    if (t + 1 < TSTEPS) {
      xt_next = x[t + 1];
      if (ZTRANS) {
        float4 a = *(const float4*)(zsrc + (size_t)(t + 1) * KP + kbase);
        float4 b = *(const float4*)(zsrc + (size_t)(t + 1) * KP + kbase + 4);
        zn[0] = a.x; zn[1] = a.y; zn[2] = a.z; zn[3] = a.w;
        zn[4] = b.x; zn[5] = b.y; zn[6] = b.z; zn[7] = b.w;
      } else {
#pragma unroll
        for (int j = 0; j < PT; ++j)
          zn[j] = zsrc[(size_t)(kbase + j) * TSTEPS + t + 1];
      }
      float4 a = *(const float4*)(u + (size_t)(t + 1) * KP + kbase);
      float4 b = *(const float4*)(u + (size_t)(t + 1) * KP + kbase + 4);
      un[0] = a.x; un[1] = a.y; un[2] = a.z; un[3] = a.w;
      un[4] = b.x; un[5] = b.y; un[6] = b.z; un[7] = b.w;
    }

    float s[PT];
    float run = 0.f;
#pragma unroll
    for (int j = 0; j < PT; ++j) {
      float d = zv[j] - wv[j];
      float lw = fmaf(xt, zv[j], -0.5f * d * d);
      run += __expf(lw);
      s[j] = run;
    }
    const float wincl = wscan64_add(run);
    const float wexcl = wincl - run;
    if (lane == 63) red[wid] = wincl;
    __syncthreads();

    float v16 = rscan16_add(red[lane & 15]);
    const float total = readlane_f(v16, 15);
    const float wpre = wid ? readlane_f(v16, wid - 1) : 0.f;
    const float base = wpre + wexcl;
    const float invT = 1.0f / total;

    float cvn[PT];
#pragma unroll
    for (int j = 0; j < PT; ++j) cvn[j] = (base + s[j]) * invT;
    {
      float4 a, b;
      a.x = cvn[0]; a.y = cvn[1]; a.z = cvn[2]; a.w = cvn[3];
      b.x = cvn[4]; b.y = cvn[5]; b.z = cvn[6]; b.w = cvn[7];
      *(float4*)(cdf_s + kbase) = a;
      *(float4*)(cdf_s + kbase + 4) = b;
    }
    cend[tid] = cvn[PT - 1];
    if (tid == BLOCK - 1) bcI[0] = (int)(cvn[PT - 1] * NBF);
    {
      int4 z4; z4.x = z4.y = z4.z = z4.w = 0;
      *(int4*)(L_s + kbase) = z4;
      *(int4*)(L_s + kbase + 4) = z4;
    }
    if (tid == 0)
      acc += __logf(total) - 9.0109133472792886f
             - 0.5f * (1.8378770664093453f + xt * xt);
    __syncthreads();

    {
      const float cprev = tid ? cend[tid - 1] : 0.f;
      int flo = (int)(cprev * NBF);
#pragma unroll
      for (int j = 0; j < PT; ++j) {
        int fhi = (int)(cvn[j] * NBF);
        if (fhi > NBUCK - 1) fhi = NBUCK - 1;
        if (fhi > flo) L_s[flo + 1] = kbase + j;
        flo = fhi;
      }
    }
    __syncthreads();

    int4 ra = *(const int4*)(L_s + kbase);
    int4 rb = *(const int4*)(L_s + kbase + 4);
    int c1 = max(ra.x, ra.y);
    int c2 = max(c1, ra.z);
    int c3 = max(c2, ra.w);
    int c4 = max(c3, rb.x);
    int c5 = max(c4, rb.y);
    int c6 = max(c5, rb.z);
    int c7 = max(c6, rb.w);
    const int mincl = wscan64_max(c7);
    int mexcl = __shfl_up(mincl, 1);
    if (lane == 0) mexcl = 0;
    if (lane == 63) redi[wid] = mincl;
    __syncthreads();

    {
      int mv = rscan16_max(redi[lane & 15]);
      const int crosspre = wid ? __builtin_amdgcn_readlane(mv, wid - 1) : 0;
      const int fhiLast = bcI[0];
      int m = max(crosspre, mexcl);
      int4 oa, ob;
      m = max(m, ra.x); oa.x = (kbase + 0 > fhiLast) ? (KP - 1) : m;
      m = max(m, ra.y); oa.y = (kbase + 1 > fhiLast) ? (KP - 1) : m;
      m = max(m, ra.z); oa.z = (kbase + 2 > fhiLast) ? (KP - 1) : m;
      m = max(m, ra.w); oa.w = (kbase + 3 > fhiLast) ? (KP - 1) : m;
      m = max(m, rb.x); ob.x = (kbase + 4 > fhiLast) ? (KP - 1) : m;
      m = max(m, rb.y); ob.y = (kbase + 5 > fhiLast) ? (KP - 1) : m;
      m = max(m, rb.z); ob.z = (kbase + 6 > fhiLast) ? (KP - 1) : m;
      m = max(m, rb.w); ob.w = (kbase + 7 > fhiLast) ? (KP - 1) : m;
      *(int4*)(L_s + kbase) = oa;
      *(int4*)(L_s + kbase + 4) = ob;
    }
    __syncthreads();

    int lo[PT], len[PT];
    float tg[PT];
    int anylen = 0;
#pragma unroll
    for (int j = 0; j < PT; ++j) {
      tg[j] = uv[j];
      const float fb = uv[j] * NBF;
      int b = (int)fb;
      b = min(b, NBUCK - 1);
      const int i0 = L_s[b];
      const int i1 = L_s[b + 1];
      lo[j] = i0;
      len[j] = i1 - i0;
      anylen |= len[j];
    }
    while (anylen) {
      anylen = 0;
#pragma unroll
      for (int j = 0; j < PT; ++j) {
        const int half = len[j] >> 1;
        const float c = cdf_s[lo[j] + half];
        const bool adv = (c < tg[j]) & (len[j] > 0);
        lo[j] = adv ? lo[j] + half + 1 : lo[j];
        len[j] = adv ? len[j] - half - 1 : half;
        anylen |= len[j];
      }
    }

    float nw[PT];
#pragma unroll
    for (int j = 0; j < PT; ++j) nw[j] = wcur[lo[j]];
    {
      float4 a, b;
      a.x = nw[0]; a.y = nw[1]; a.z = nw[2]; a.w = nw[3];
      b.x = nw[4]; b.y = nw[5]; b.z = nw[6]; b.w = nw[7];
      *(float4*)(wnxt + kbase) = a;
      *(float4*)(wnxt + kbase + 4) = b;
    }
#pragma unroll
    for (int j = 0; j < PT; ++j) wv[j] = nw[j];
    float* tmp = wcur; wcur = wnxt; wnxt = tmp;
  }

  if (tid == 0) out[0] = acc;
}

// ---------------------------------------------------------------------------
extern "C" void kernel_launch(void* const* d_in, const int* in_sizes, int n_in,
                              void* d_out, int out_size, void* d_ws, size_t ws_size,
                              hipStream_t stream) {
  const float* x = (const float*)d_in[0];   // [T]
  const float* w0 = (const float*)d_in[1];  // [K]
  const float* z = (const float*)d_in[2];   // [K,T]
  const float* u = (const float*)d_in[3];   // [T,K]
  float* out = (float*)d_out;

  const size_t SZ_ZT = (size_t)KP * TSTEPS * sizeof(float);  // 128 MiB
  const size_t OFF_SCR = SZ_ZT + (64u << 20);                // scratch well past zT

  const size_t shmem_prod =
      (size_t)(3 * KP + BLOCK + NWAVES + NWAVES + 4 + NBUCK + 1) * sizeof(float);
  const size_t shmem_core = (size_t)(3 * KP + NWAVES) * sizeof(float);

  if (ws_size >= SZ_ZT) {
    float* zT = (float*)d_ws;
    transpose_k<<<dim3(TSTEPS / 32, KP / 32), dim3(32, 8), 0, stream>>>(z, zT);
    // EXPERIMENT (result to scratch; timing read from dur/rocprof):
    if (ws_size >= OFF_SCR + 64) {
      float* scr = (float*)((char*)d_ws + OFF_SCR);
      smc_core<<<1, BLOCK, shmem_core, stream>>>(x, w0, zT, u, scr);
    }
    // PRODUCTION (validated output):
    smc_scan<true><<<1, BLOCK, shmem_prod, stream>>>(x, w0, zT, u, out);
  } else {
    smc_scan<false><<<1, BLOCK, shmem_prod, stream>>>(x, w0, z, u, out);
  }
}

// Round 12
// 23671.800 us; speedup vs baseline: 1.0039x; 1.0039x over previous
//
#include <hip/hip_runtime.h>
#include <math.h>

#define KP 8192
#define TSTEPS 4096
#define BLOCK 1024
#define PT 8
#define NWAVES 16
#define NBUCK 8192
#define NBF 8192.0f

// ---------------- DPP wave-scan helpers (pure VALU, no LDS pipe) ----------------
template <int CTRL, int RM>
__device__ __forceinline__ float dpp_add_f(float x) {
  int s = __builtin_amdgcn_update_dpp(0, __float_as_int(x), CTRL, RM, 0xF, false);
  return x + __int_as_float(s);
}
template <int CTRL, int RM>
__device__ __forceinline__ int dpp_add_i(int x) {
  int s = __builtin_amdgcn_update_dpp(0, x, CTRL, RM, 0xF, false);
  return x + s;
}
template <int CTRL, int RM>
__device__ __forceinline__ int dpp_max_i(int x) {
  int s = __builtin_amdgcn_update_dpp(0, x, CTRL, RM, 0xF, false);
  return x > s ? x : s;
}
__device__ __forceinline__ float wscan64_add(float x) {
  x = dpp_add_f<0x111, 0xF>(x); x = dpp_add_f<0x112, 0xF>(x);
  x = dpp_add_f<0x114, 0xF>(x); x = dpp_add_f<0x118, 0xF>(x);
  x = dpp_add_f<0x142, 0xA>(x); x = dpp_add_f<0x143, 0xC>(x);
  return x;
}
__device__ __forceinline__ int wscan64_addi(int x) {
  x = dpp_add_i<0x111, 0xF>(x); x = dpp_add_i<0x112, 0xF>(x);
  x = dpp_add_i<0x114, 0xF>(x); x = dpp_add_i<0x118, 0xF>(x);
  x = dpp_add_i<0x142, 0xA>(x); x = dpp_add_i<0x143, 0xC>(x);
  return x;
}
__device__ __forceinline__ int wscan64_max(int x) {
  x = dpp_max_i<0x111, 0xF>(x); x = dpp_max_i<0x112, 0xF>(x);
  x = dpp_max_i<0x114, 0xF>(x); x = dpp_max_i<0x118, 0xF>(x);
  x = dpp_max_i<0x142, 0xA>(x); x = dpp_max_i<0x143, 0xC>(x);
  return x;
}
__device__ __forceinline__ float rscan16_add(float x) {
  x = dpp_add_f<0x111, 0xF>(x); x = dpp_add_f<0x112, 0xF>(x);
  x = dpp_add_f<0x114, 0xF>(x); x = dpp_add_f<0x118, 0xF>(x);
  return x;
}
__device__ __forceinline__ int rscan16_addi(int x) {
  x = dpp_add_i<0x111, 0xF>(x); x = dpp_add_i<0x112, 0xF>(x);
  x = dpp_add_i<0x114, 0xF>(x); x = dpp_add_i<0x118, 0xF>(x);
  return x;
}
__device__ __forceinline__ int rscan16_max(int x) {
  x = dpp_max_i<0x111, 0xF>(x); x = dpp_max_i<0x112, 0xF>(x);
  x = dpp_max_i<0x114, 0xF>(x); x = dpp_max_i<0x118, 0xF>(x);
  return x;
}
__device__ __forceinline__ float readlane_f(float v, int l) {
  return __int_as_float(__builtin_amdgcn_readlane(__float_as_int(v), l));
}

// ---------------------------------------------------------------------------
// Transpose z [KP][TSTEPS] -> zT [TSTEPS][KP].
// ---------------------------------------------------------------------------
__global__ void transpose_k(const float* __restrict__ in, float* __restrict__ out) {
  __shared__ float tile[32][33];
  const int c0 = blockIdx.x * 32;
  const int r0 = blockIdx.y * 32;
  const int tx = threadIdx.x;
  const int ty = threadIdx.y;
#pragma unroll
  for (int i = 0; i < 32; i += 8)
    tile[ty + i][tx] = in[(size_t)(r0 + ty + i) * TSTEPS + c0 + tx];
  __syncthreads();
#pragma unroll
  for (int i = 0; i < 32; i += 8)
    out[(size_t)(c0 + ty + i) * KP + r0 + tx] = tile[tx][ty + i];
}

// ---------------------------------------------------------------------------
// One-time per-step bucket sort of u: sorted su[t][K] + rank rank[t][k] (u16).
// ---------------------------------------------------------------------------
__global__ __launch_bounds__(BLOCK) void sortu_k(const float* __restrict__ u,
                                                 float* __restrict__ su,
                                                 unsigned short* __restrict__ rnk) {
  __shared__ int hist[NBUCK];
  __shared__ float sval[KP];
  __shared__ unsigned short sidx[KP];
  __shared__ int redi[NWAVES];
  const int t = blockIdx.x;
  const int tid = threadIdx.x;
  const int lane = tid & 63;
  const int wid = tid >> 6;
  const int kbase = tid * PT;

  float uv[PT];
  {
    float4 a = *(const float4*)(u + (size_t)t * KP + kbase);
    float4 b = *(const float4*)(u + (size_t)t * KP + kbase + 4);
    uv[0] = a.x; uv[1] = a.y; uv[2] = a.z; uv[3] = a.w;
    uv[4] = b.x; uv[5] = b.y; uv[6] = b.z; uv[7] = b.w;
  }
  int bj[PT];
#pragma unroll
  for (int j = 0; j < PT; ++j) {
    int b = (int)(uv[j] * NBF);
    bj[j] = b > NBUCK - 1 ? NBUCK - 1 : b;
  }
  {
    int4 z4; z4.x = z4.y = z4.z = z4.w = 0;
    *(int4*)(hist + kbase) = z4;
    *(int4*)(hist + kbase + 4) = z4;
  }
  __syncthreads();
#pragma unroll
  for (int j = 0; j < PT; ++j) atomicAdd(&hist[bj[j]], 1);
  __syncthreads();

  int4 ha = *(const int4*)(hist + kbase);
  int4 hb = *(const int4*)(hist + kbase + 4);
  int c0 = ha.x, c1 = c0 + ha.y, c2 = c1 + ha.z, c3 = c2 + ha.w;
  int c4 = c3 + hb.x, c5 = c4 + hb.y, c6 = c5 + hb.z, c7 = c6 + hb.w;
  int wincl = wscan64_addi(c7);
  int wexcl = wincl - c7;
  if (lane == 63) redi[wid] = wincl;
  __syncthreads();
  int v16 = rscan16_addi(redi[lane & 15]);
  int cp = wid ? __builtin_amdgcn_readlane(v16, wid - 1) : 0;
  int base = cp + wexcl;
  {
    int4 pa; pa.x = base; pa.y = base + c0; pa.z = base + c1; pa.w = base + c2;
    int4 pb; pb.x = base + c3; pb.y = base + c4; pb.z = base + c5; pb.w = base + c6;
    *(int4*)(hist + kbase) = pa;
    *(int4*)(hist + kbase + 4) = pb;
  }
  __syncthreads();
#pragma unroll
  for (int j = 0; j < PT; ++j) {
    int pos = atomicAdd(&hist[bj[j]], 1);
    sval[pos] = uv[j];
    sidx[pos] = (unsigned short)(kbase + j);
  }
  __syncthreads();
  for (int bb = tid; bb < NBUCK; bb += BLOCK) {
    int s0 = bb ? hist[bb - 1] : 0;
    int e0 = hist[bb];
    for (int m = s0 + 1; m < e0; ++m) {
      float v = sval[m];
      unsigned short ix = sidx[m];
      int p = m - 1;
      while (p >= s0 && sval[p] > v) {
        sval[p + 1] = sval[p];
        sidx[p + 1] = sidx[p];
        --p;
      }
      sval[p + 1] = v;
      sidx[p + 1] = ix;
    }
  }
  __syncthreads();
  {
    float4 a, b;
    a.x = sval[kbase + 0]; a.y = sval[kbase + 1]; a.z = sval[kbase + 2]; a.w = sval[kbase + 3];
    b.x = sval[kbase + 4]; b.y = sval[kbase + 5]; b.z = sval[kbase + 6]; b.w = sval[kbase + 7];
    *(float4*)(su + (size_t)t * KP + kbase) = a;
    *(float4*)(su + (size_t)t * KP + kbase + 4) = b;
  }
#pragma unroll
  for (int j = 0; j < PT; ++j)
    rnk[(size_t)t * KP + sidx[kbase + j]] = (unsigned short)(kbase + j);
}

// ---------------------------------------------------------------------------
// Tier-A: round-6 machinery with RANK-ORDER queries (sorted su).
// Same buckets/windows/predicates as round 6 (bit-identical idx); sortedness
// makes probe + gather addresses monotone across the wave (conflict-light),
// and answers land in rank order -> inversion is a contiguous P2 write +
// one rank gather. 6 barriers/step.
// ---------------------------------------------------------------------------
__global__ __launch_bounds__(BLOCK) void smc_scan5(
    const float* __restrict__ x, const float* __restrict__ w0,
    const float* __restrict__ zsrc, const float* __restrict__ su_g,
    const unsigned short* __restrict__ rk_g, float* __restrict__ out) {
  extern __shared__ float sm[];
  float* w_s = sm;               // KP   particle values (slot order)
  float* cdf_s = sm + KP;        // KP   normalized cdf
  float* P2_s = cdf_s + KP;      // KP   rank -> resampled value
  float* cend = P2_s + KP;       // BLOCK per-thread cdf end
  float* red = cend + BLOCK;     // NWAVES
  int* redi = (int*)(red + NWAVES);
  int* bcI = redi + NWAVES;      // 4
  int* L_s = bcI + 4;            // NBUCK+1

  const int tid = threadIdx.x;
  const int lane = tid & 63;
  const int wid = tid >> 6;
  const int kbase = tid * PT;

  for (int i = tid; i < NBUCK; i += BLOCK) L_s[i] = 0;
  if (tid == 0) L_s[NBUCK] = KP - 1;

  float wv[PT];
  {
    float4 a = *(const float4*)(w0 + kbase);
    float4 b = *(const float4*)(w0 + kbase + 4);
    wv[0] = a.x; wv[1] = a.y; wv[2] = a.z; wv[3] = a.w;
    wv[4] = b.x; wv[5] = b.y; wv[6] = b.z; wv[7] = b.w;
    *(float4*)(w_s + kbase) = a;
    *(float4*)(w_s + kbase + 4) = b;
  }
  __syncthreads();

  // Prefetch registers (step 0).
  float4 zna, znb, sna, snb;
  int4 rkn;
  float xt_next = x[0];
  zna = *(const float4*)(zsrc + kbase);
  znb = *(const float4*)(zsrc + kbase + 4);
  sna = *(const float4*)(su_g + kbase);
  snb = *(const float4*)(su_g + kbase + 4);
  rkn = *(const int4*)(rk_g + kbase);

  float acc = 0.f;

  for (int t = 0; t < TSTEPS; ++t) {
    float zv[PT], suv[PT];
    zv[0] = zna.x; zv[1] = zna.y; zv[2] = zna.z; zv[3] = zna.w;
    zv[4] = znb.x; zv[5] = znb.y; zv[6] = znb.z; zv[7] = znb.w;
    suv[0] = sna.x; suv[1] = sna.y; suv[2] = sna.z; suv[3] = sna.w;
    suv[4] = snb.x; suv[5] = snb.y; suv[6] = snb.z; suv[7] = snb.w;
    const int4 rkc = rkn;
    const float xt = xt_next;

    if (t + 1 < TSTEPS) {
      xt_next = x[t + 1];
      const size_t ro = (size_t)(t + 1) * KP + kbase;
      zna = *(const float4*)(zsrc + ro);
      znb = *(const float4*)(zsrc + ro + 4);
      sna = *(const float4*)(su_g + ro);
      snb = *(const float4*)(su_g + ro + 4);
      rkn = *(const int4*)(rk_g + ro);
    }

    // ---- A: weights, exp, thread-local scan, DPP wave scan (as round 6).
    float s[PT];
    float run = 0.f;
#pragma unroll
    for (int j = 0; j < PT; ++j) {
      float d = zv[j] - wv[j];
      float lw = fmaf(xt, zv[j], -0.5f * d * d);
      run += __expf(lw);
      s[j] = run;
    }
    const float wincl = wscan64_add(run);
    const float wexcl = wincl - run;
    if (lane == 63) red[wid] = wincl;
    __syncthreads();  // B1

    // ---- B: cross-wave scan; normalized cdf write; cend; clear L.
    float v16 = rscan16_add(red[lane & 15]);
    const float total = readlane_f(v16, 15);
    const float wpre = wid ? readlane_f(v16, wid - 1) : 0.f;
    const float base = wpre + wexcl;
    const float invT = 1.0f / total;

    float cvn[PT];
#pragma unroll
    for (int j = 0; j < PT; ++j) cvn[j] = (base + s[j]) * invT;
    {
      float4 a, b;
      a.x = cvn[0]; a.y = cvn[1]; a.z = cvn[2]; a.w = cvn[3];
      b.x = cvn[4]; b.y = cvn[5]; b.z = cvn[6]; b.w = cvn[7];
      *(float4*)(cdf_s + kbase) = a;
      *(float4*)(cdf_s + kbase + 4) = b;
    }
    cend[tid] = cvn[PT - 1];
    if (tid == BLOCK - 1) bcI[0] = (int)(cvn[PT - 1] * NBF);
    {
      int4 z4; z4.x = z4.y = z4.z = z4.w = 0;
      *(int4*)(L_s + kbase) = z4;
      *(int4*)(L_s + kbase + 4) = z4;
    }
    if (tid == 0)
      acc += __logf(total) - 9.0109133472792886f   // log(K)
             - 0.5f * (1.8378770664093453f + xt * xt);
    __syncthreads();  // B2

    // ---- C2a: bucket scatter (identical to round 6).
    {
      const float cprev = tid ? cend[tid - 1] : 0.f;
      int flo = (int)(cprev * NBF);
#pragma unroll
      for (int j = 0; j < PT; ++j) {
        int fhi = (int)(cvn[j] * NBF);
        if (fhi > NBUCK - 1) fhi = NBUCK - 1;
        if (fhi > flo) L_s[flo + 1] = kbase + j;
        flo = fhi;
      }
    }
    __syncthreads();  // B3

    // ---- C2b: local + wave max-scan over L.
    int4 ra = *(const int4*)(L_s + kbase);
    int4 rb = *(const int4*)(L_s + kbase + 4);
    int c1 = max(ra.x, ra.y);
    int c2 = max(c1, ra.z);
    int c3 = max(c2, ra.w);
    int c4 = max(c3, rb.x);
    int c5 = max(c4, rb.y);
    int c6 = max(c5, rb.z);
    int c7 = max(c6, rb.w);
    const int mincl = wscan64_max(c7);
    int mexcl = __shfl_up(mincl, 1);
    if (lane == 0) mexcl = 0;
    if (lane == 63) redi[wid] = mincl;
    __syncthreads();  // B4

    // ---- C2c: cross-wave max, finalize L + topfix.
    {
      int mv = rscan16_max(redi[lane & 15]);
      const int crosspre = wid ? __builtin_amdgcn_readlane(mv, wid - 1) : 0;
      const int fhiLast = bcI[0];
      int m = max(crosspre, mexcl);
      int4 oa, ob;
      m = max(m, ra.x); oa.x = (kbase + 0 > fhiLast) ? (KP - 1) : m;
      m = max(m, ra.y); oa.y = (kbase + 1 > fhiLast) ? (KP - 1) : m;
      m = max(m, ra.z); oa.z = (kbase + 2 > fhiLast) ? (KP - 1) : m;
      m = max(m, ra.w); oa.w = (kbase + 3 > fhiLast) ? (KP - 1) : m;
      m = max(m, rb.x); ob.x = (kbase + 4 > fhiLast) ? (KP - 1) : m;
      m = max(m, rb.y); ob.y = (kbase + 5 > fhiLast) ? (KP - 1) : m;
      m = max(m, rb.z); ob.z = (kbase + 6 > fhiLast) ? (KP - 1) : m;
      m = max(m, rb.w); ob.w = (kbase + 7 > fhiLast) ? (KP - 1) : m;
      *(int4*)(L_s + kbase) = oa;
      *(int4*)(L_s + kbase + 4) = ob;
    }
    __syncthreads();  // B5

    // ---- D: bucketed binary search, queries = SORTED su (rank order).
    // Identical windows+predicate as round 6 -> bit-identical answers;
    // monotone probe addresses across the wave -> conflict-light.
    int lo[PT], len[PT];
    int anylen = 0;
#pragma unroll
    for (int j = 0; j < PT; ++j) {
      const float fb = suv[j] * NBF;
      int b = (int)fb;
      b = min(b, NBUCK - 1);
      const int i0 = L_s[b];
      const int i1 = L_s[b + 1];
      lo[j] = i0;
      len[j] = i1 - i0;
      anylen |= len[j];
    }
    while (anylen) {
      anylen = 0;
#pragma unroll
      for (int j = 0; j < PT; ++j) {
        const int half = len[j] >> 1;
        const float c = cdf_s[lo[j] + half];
        const bool adv = (c < suv[j]) & (len[j] > 0);
        lo[j] = adv ? lo[j] + half + 1 : lo[j];
        len[j] = adv ? len[j] - half - 1 : half;
        anylen |= len[j];
      }
    }

    // ---- E: monotone gather + contiguous rank-order store.
    {
      float pv[PT];
#pragma unroll
      for (int j = 0; j < PT; ++j) pv[j] = w_s[lo[j]];  // sorted addrs
      float4 a, b;
      a.x = pv[0]; a.y = pv[1]; a.z = pv[2]; a.w = pv[3];
      b.x = pv[4]; b.y = pv[5]; b.z = pv[6]; b.w = pv[7];
      *(float4*)(P2_s + kbase) = a;
      *(float4*)(P2_s + kbase + 4) = b;
    }
    __syncthreads();  // B6

    // ---- F: invert via rank lookup; refresh w_s (single buffer: all reads
    // of old w_s finished before B6).
    {
      const int r0 = rkc.x & 0xffff, r1 = (rkc.x >> 16) & 0xffff;
      const int r2 = rkc.y & 0xffff, r3 = (rkc.y >> 16) & 0xffff;
      const int r4 = rkc.z & 0xffff, r5 = (rkc.z >> 16) & 0xffff;
      const int r6 = rkc.w & 0xffff, r7 = (rkc.w >> 16) & 0xffff;
      wv[0] = P2_s[r0]; wv[1] = P2_s[r1]; wv[2] = P2_s[r2]; wv[3] = P2_s[r3];
      wv[4] = P2_s[r4]; wv[5] = P2_s[r5]; wv[6] = P2_s[r6]; wv[7] = P2_s[r7];
      float4 a, b;
      a.x = wv[0]; a.y = wv[1]; a.z = wv[2]; a.w = wv[3];
      b.x = wv[4]; b.y = wv[5]; b.z = wv[6]; b.w = wv[7];
      *(float4*)(w_s + kbase) = a;   // next read: E of step t+1 (post B1..B5)
      *(float4*)(w_s + kbase + 4) = b;
    }
  }

  if (tid == 0) out[0] = acc;
}

// ---------------------------------------------------------------------------
// Tier-B fallback: proven round-6 kernel.
// ---------------------------------------------------------------------------
template <bool ZTRANS>
__global__ __launch_bounds__(BLOCK) void smc_scan(const float* __restrict__ x,
                                                  const float* __restrict__ w0,
                                                  const float* __restrict__ zsrc,
                                                  const float* __restrict__ u,
                                                  float* __restrict__ out) {
  extern __shared__ float sm[];
  float* wbufA = sm;
  float* wbufB = sm + KP;
  float* cdf_s = sm + 2 * KP;
  float* cend = cdf_s + KP;
  float* red = cend + BLOCK;
  int* redi = (int*)(red + NWAVES);
  int* bcI = redi + NWAVES;
  int* L_s = bcI + 4;

  const int tid = threadIdx.x;
  const int lane = tid & 63;
  const int wid = tid >> 6;
  const int kbase = tid * PT;

  float* wcur = wbufA;
  float* wnxt = wbufB;

  for (int i = tid; i < NBUCK; i += BLOCK) L_s[i] = 0;
  if (tid == 0) L_s[NBUCK] = KP - 1;

  float wv[PT];
  {
    float4 a = *(const float4*)(w0 + kbase);
    float4 b = *(const float4*)(w0 + kbase + 4);
    wv[0] = a.x; wv[1] = a.y; wv[2] = a.z; wv[3] = a.w;
    wv[4] = b.x; wv[5] = b.y; wv[6] = b.z; wv[7] = b.w;
    *(float4*)(wcur + kbase) = a;
    *(float4*)(wcur + kbase + 4) = b;
  }
  __syncthreads();

  float zn[PT], un[PT];
  float xt_next = x[0];
  if (ZTRANS) {
    float4 a = *(const float4*)(zsrc + kbase);
    float4 b = *(const float4*)(zsrc + kbase + 4);
    zn[0] = a.x; zn[1] = a.y; zn[2] = a.z; zn[3] = a.w;
    zn[4] = b.x; zn[5] = b.y; zn[6] = b.z; zn[7] = b.w;
  } else {
#pragma unroll
    for (int j = 0; j < PT; ++j) zn[j] = zsrc[(size_t)(kbase + j) * TSTEPS];
  }
  {
    float4 a = *(const float4*)(u + kbase);
    float4 b = *(const float4*)(u + kbase + 4);
    un[0] = a.x; un[1] = a.y; un[2] = a.z; un[3] = a.w;
    un[4] = b.x; un[5] = b.y; un[6] = b.z; un[7] = b.w;
  }

  float acc = 0.f;

  for (int t = 0; t < TSTEPS; ++t) {
    float zv[PT], uv[PT];
#pragma unroll
    for (int j = 0; j < PT; ++j) { zv[j] = zn[j]; uv[j] = un[j]; }
    const float xt = xt_next;

    if (t + 1 < TSTEPS) {
      xt_next = x[t + 1];
      if (ZTRANS) {
        float4 a = *(const float4*)(zsrc + (size_t)(t + 1) * KP + kbase);
        float4 b = *(const float4*)(zsrc + (size_t)(t + 1) * KP + kbase + 4);
        zn[0] = a.x; zn[1] = a.y; zn[2] = a.z; zn[3] = a.w;
        zn[4] = b.x; zn[5] = b.y; zn[6] = b.z; zn[7] = b.w;
      } else {
#pragma unroll
        for (int j = 0; j < PT; ++j)
          zn[j] = zsrc[(size_t)(kbase + j) * TSTEPS + t + 1];
      }
      float4 a = *(const float4*)(u + (size_t)(t + 1) * KP + kbase);
      float4 b = *(const float4*)(u + (size_t)(t + 1) * KP + kbase + 4);
      un[0] = a.x; un[1] = a.y; un[2] = a.z; un[3] = a.w;
      un[4] = b.x; un[5] = b.y; un[6] = b.z; un[7] = b.w;
    }

    float s[PT];
    float run = 0.f;
#pragma unroll
    for (int j = 0; j < PT; ++j) {
      float d = zv[j] - wv[j];
      float lw = fmaf(xt, zv[j], -0.5f * d * d);
      run += __expf(lw);
      s[j] = run;
    }
    const float wincl = wscan64_add(run);
    const float wexcl = wincl - run;
    if (lane == 63) red[wid] = wincl;
    __syncthreads();

    float v16 = rscan16_add(red[lane & 15]);
    const float total = readlane_f(v16, 15);
    const float wpre = wid ? readlane_f(v16, wid - 1) : 0.f;
    const float base = wpre + wexcl;
    const float invT = 1.0f / total;

    float cvn[PT];
#pragma unroll
    for (int j = 0; j < PT; ++j) cvn[j] = (base + s[j]) * invT;
    {
      float4 a, b;
      a.x = cvn[0]; a.y = cvn[1]; a.z = cvn[2]; a.w = cvn[3];
      b.x = cvn[4]; b.y = cvn[5]; b.z = cvn[6]; b.w = cvn[7];
      *(float4*)(cdf_s + kbase) = a;
      *(float4*)(cdf_s + kbase + 4) = b;
    }
    cend[tid] = cvn[PT - 1];
    if (tid == BLOCK - 1) bcI[0] = (int)(cvn[PT - 1] * NBF);
    {
      int4 z4; z4.x = z4.y = z4.z = z4.w = 0;
      *(int4*)(L_s + kbase) = z4;
      *(int4*)(L_s + kbase + 4) = z4;
    }
    if (tid == 0)
      acc += __logf(total) - 9.0109133472792886f
             - 0.5f * (1.8378770664093453f + xt * xt);
    __syncthreads();

    {
      const float cprev = tid ? cend[tid - 1] : 0.f;
      int flo = (int)(cprev * NBF);
#pragma unroll
      for (int j = 0; j < PT; ++j) {
        int fhi = (int)(cvn[j] * NBF);
        if (fhi > NBUCK - 1) fhi = NBUCK - 1;
        if (fhi > flo) L_s[flo + 1] = kbase + j;
        flo = fhi;
      }
    }
    __syncthreads();

    int4 ra = *(const int4*)(L_s + kbase);
    int4 rb = *(const int4*)(L_s + kbase + 4);
    int c1 = max(ra.x, ra.y);
    int c2 = max(c1, ra.z);
    int c3 = max(c2, ra.w);
    int c4 = max(c3, rb.x);
    int c5 = max(c4, rb.y);
    int c6 = max(c5, rb.z);
    int c7 = max(c6, rb.w);
    const int mincl = wscan64_max(c7);
    int mexcl = __shfl_up(mincl, 1);
    if (lane == 0) mexcl = 0;
    if (lane == 63) redi[wid] = mincl;
    __syncthreads();

    {
      int mv = rscan16_max(redi[lane & 15]);
      const int crosspre = wid ? __builtin_amdgcn_readlane(mv, wid - 1) : 0;
      const int fhiLast = bcI[0];
      int m = max(crosspre, mexcl);
      int4 oa, ob;
      m = max(m, ra.x); oa.x = (kbase + 0 > fhiLast) ? (KP - 1) : m;
      m = max(m, ra.y); oa.y = (kbase + 1 > fhiLast) ? (KP - 1) : m;
      m = max(m, ra.z); oa.z = (kbase + 2 > fhiLast) ? (KP - 1) : m;
      m = max(m, ra.w); oa.w = (kbase + 3 > fhiLast) ? (KP - 1) : m;
      m = max(m, rb.x); ob.x = (kbase + 4 > fhiLast) ? (KP - 1) : m;
      m = max(m, rb.y); ob.y = (kbase + 5 > fhiLast) ? (KP - 1) : m;
      m = max(m, rb.z); ob.z = (kbase + 6 > fhiLast) ? (KP - 1) : m;
      m = max(m, rb.w); ob.w = (kbase + 7 > fhiLast) ? (KP - 1) : m;
      *(int4*)(L_s + kbase) = oa;
      *(int4*)(L_s + kbase + 4) = ob;
    }
    __syncthreads();

    int lo[PT], len[PT];
    float tg[PT];
    int anylen = 0;
#pragma unroll
    for (int j = 0; j < PT; ++j) {
      tg[j] = uv[j];
      const float fb = uv[j] * NBF;
      int b = (int)fb;
      b = min(b, NBUCK - 1);
      const int i0 = L_s[b];
      const int i1 = L_s[b + 1];
      lo[j] = i0;
      len[j] = i1 - i0;
      anylen |= len[j];
    }
    while (anylen) {
      anylen = 0;
#pragma unroll
      for (int j = 0; j < PT; ++j) {
        const int half = len[j] >> 1;
        const float c = cdf_s[lo[j] + half];
        const bool adv = (c < tg[j]) & (len[j] > 0);
        lo[j] = adv ? lo[j] + half + 1 : lo[j];
        len[j] = adv ? len[j] - half - 1 : half;
        anylen |= len[j];
      }
    }

    float nw[PT];
#pragma unroll
    for (int j = 0; j < PT; ++j) nw[j] = wcur[lo[j]];
    {
      float4 a, b;
      a.x = nw[0]; a.y = nw[1]; a.z = nw[2]; a.w = nw[3];
      b.x = nw[4]; b.y = nw[5]; b.z = nw[6]; b.w = nw[7];
      *(float4*)(wnxt + kbase) = a;
      *(float4*)(wnxt + kbase + 4) = b;
    }
#pragma unroll
    for (int j = 0; j < PT; ++j) wv[j] = nw[j];
    float* tmp = wcur; wcur = wnxt; wnxt = tmp;
  }

  if (tid == 0) out[0] = acc;
}

// ---------------------------------------------------------------------------
extern "C" void kernel_launch(void* const* d_in, const int* in_sizes, int n_in,
                              void* d_out, int out_size, void* d_ws, size_t ws_size,
                              hipStream_t stream) {
  const float* x = (const float*)d_in[0];   // [T]
  const float* w0 = (const float*)d_in[1];  // [K]
  const float* z = (const float*)d_in[2];   // [K,T]
  const float* u = (const float*)d_in[3];   // [T,K]
  float* out = (float*)d_out;

  const size_t SZ_ZT = (size_t)KP * TSTEPS * sizeof(float);      // 128 MiB
  const size_t OFF_SU = SZ_ZT;
  const size_t SZ_SU = SZ_ZT;                                    // 128 MiB
  const size_t OFF_RK = OFF_SU + SZ_SU;
  const size_t SZ_RK = (size_t)KP * TSTEPS * 2;                  // 64 MiB
  const size_t FULL = OFF_RK + SZ_RK;                            // 320 MiB

  if (ws_size >= FULL) {
    char* ws = (char*)d_ws;
    float* zT = (float*)ws;
    float* su = (float*)(ws + OFF_SU);
    unsigned short* rk = (unsigned short*)(ws + OFF_RK);
    transpose_k<<<dim3(TSTEPS / 32, KP / 32), dim3(32, 8), 0, stream>>>(z, zT);
    sortu_k<<<TSTEPS, BLOCK, 0, stream>>>(u, su, rk);
    const size_t shmem5 =
        (size_t)(3 * KP + BLOCK + NWAVES) * sizeof(float) +
        (size_t)(NWAVES + 4 + NBUCK + 1) * sizeof(int);
    smc_scan5<<<1, BLOCK, shmem5, stream>>>(x, w0, zT, su, rk, out);
  } else {
    const size_t shmem =
        (size_t)(3 * KP + BLOCK + NWAVES + NWAVES + 4 + NBUCK + 1) * sizeof(float);
    if (ws_size >= SZ_ZT) {
      float* zT = (float*)d_ws;
      transpose_k<<<dim3(TSTEPS / 32, KP / 32), dim3(32, 8), 0, stream>>>(z, zT);
      smc_scan<true><<<1, BLOCK, shmem, stream>>>(x, w0, zT, u, out);
    } else {
      smc_scan<false><<<1, BLOCK, shmem, stream>>>(x, w0, z, u, out);
    }
  }
}